// Round 1
// 268.788 us; speedup vs baseline: 1.1190x; 1.1190x over previous
//
#include <hip/hip_runtime.h>
#include <math.h>

#define NUM_POINTS 64
#define OUT_DIMS 128
#define BLOCK_THREADS 256
#define ELEMS_PER_BLOCK 256
#define PAD_LO 4
#define PAD_HI 4
#define LDS_ROWS (NUM_POINTS + PAD_LO + PAD_HI)  // 72 rows

// Weights: w_j = cos^2(pi*d_j/8) with d_j = t - j, t = xs - p0 in [3,4).
// Identity: cos^2(pi*d/8) = 0.5 + 0.5*cos(pi*d/4); the 8 taps are spaced
// pi/4 apart, so all 8 weights come from ONE sin + ONE cos of pi*t/4.
// Interior elements (all taps in [0,64)): the 8 cos terms cancel exactly,
// wsum == 4, so weights are built directly at final scale (0.125 + ...).
__global__ __launch_bounds__(BLOCK_THREADS) void ce_kernel(
    const float* __restrict__ x,
    const float* __restrict__ emb,
    float* __restrict__ out) {
  __shared__ float s_emb[LDS_ROWS * OUT_DIMS];  // 36864 B, rows -4..67
  __shared__ float s_x[ELEMS_PER_BLOCK];        // 1 KB

  const int tid = threadIdx.x;
  {
    // stage embeddings into rows 4..67 (16B vectorized, coalesced)
    float4* s4 = (float4*)(s_emb + PAD_LO * OUT_DIMS);
    const float4* e4 = (const float4*)emb;
#pragma unroll
    for (int i = 0; i < (NUM_POINTS * OUT_DIMS / 4) / BLOCK_THREADS; ++i)
      s4[tid + i * BLOCK_THREADS] = e4[tid + i * BLOCK_THREADS];
    // zero the pad rows (-4..-1 and 64..67): taps there contribute 0,
    // and zeroed rows mean NO address clamping anywhere.
    if (tid < (PAD_LO * OUT_DIMS / 4)) {  // 128 float4 per pad region
      ((float4*)s_emb)[tid] = make_float4(0.f, 0.f, 0.f, 0.f);
      ((float4*)(s_emb + (PAD_LO + NUM_POINTS) * OUT_DIMS))[tid] =
          make_float4(0.f, 0.f, 0.f, 0.f);
    }
    // stage this block's x chunk (1 float/thread, coalesced) so the main
    // loop never touches global memory for x.
    s_x[tid] = x[blockIdx.x * ELEMS_PER_BLOCK + tid];
  }
  __syncthreads();

  const int chunk = tid & 15;  // 16 dim-chunks: dims [4c,4c+4) and [64+4c,...)
  const int sub = tid >> 4;    // 16 elements per iteration per block
  const size_t base = (size_t)blockIdx.x * ELEMS_PER_BLOCK;
  const float RS2 = 0.70710678118654752f;  // sqrt(2)/2

#pragma unroll 2
  for (int it = 0; it < ELEMS_PER_BLOCK / 16; ++it) {
    const int e_local = it * 16 + sub;
    const float xv = s_x[e_local];           // LDS broadcast per quarter-wave
    const float xs = (xv + 1.0f) * 32.0f;    // [-1,1] -> [0,64)
    const int p0 = (int)floorf(xs) - 3;
    const float t = xs - (float)p0;          // in [3,4)
    // angle pi*t/4 rad == t/8 revolutions (v_sin/v_cos take revolutions;
    // t/8 in [0.375,0.5) so no range reduction needed)
    const float rev = t * 0.125f;
    const float c4 = 0.125f * __builtin_amdgcn_cosf(rev);
    const float s4 = 0.125f * __builtin_amdgcn_sinf(rev);
    const float u4 = RS2 * (c4 + s4);
    const float v4 = RS2 * (c4 - s4);

    float w[8];
    w[0] = 0.125f + c4;  w[1] = 0.125f + u4;
    w[2] = 0.125f + s4;  w[3] = 0.125f - v4;
    w[4] = 0.125f - c4;  w[5] = 0.125f - u4;
    w[6] = 0.125f - s4;  w[7] = 0.125f + v4;

    // Edge elements (~11%): renormalize over the in-grid taps only.
    if (__builtin_expect((unsigned)p0 > 56u, 0)) {
      float ssum = 0.f;
#pragma unroll
      for (int j = 0; j < 8; ++j) {
        w[j] = ((unsigned)(p0 + j) < 64u) ? w[j] : 0.f;
        ssum += w[j];
      }
      const float inv = __builtin_amdgcn_rcpf(ssum);  // ssum >= ~0.24 always
#pragma unroll
      for (int j = 0; j < 8; ++j) w[j] *= inv;
    }

    // 8 taps x 2 float4 per thread; single base reg + immediate offsets.
    const float* rowbase = s_emb + (p0 + PAD_LO) * OUT_DIMS + chunk * 4;
    float4 a0 = make_float4(0.f, 0.f, 0.f, 0.f);
    float4 a1 = make_float4(0.f, 0.f, 0.f, 0.f);
#pragma unroll
    for (int j = 0; j < 8; ++j) {
      const float4 e0 = *(const float4*)(rowbase + j * OUT_DIMS);
      const float4 e1 = *(const float4*)(rowbase + j * OUT_DIMS + 64);
      a0.x = fmaf(w[j], e0.x, a0.x);
      a0.y = fmaf(w[j], e0.y, a0.y);
      a0.z = fmaf(w[j], e0.z, a0.z);
      a0.w = fmaf(w[j], e0.w, a0.w);
      a1.x = fmaf(w[j], e1.x, a1.x);
      a1.y = fmaf(w[j], e1.y, a1.y);
      a1.z = fmaf(w[j], e1.z, a1.z);
      a1.w = fmaf(w[j], e1.w, a1.w);
    }
    // stores: quarter-wave (16 lanes) covers 256B contiguous per instruction
    float* op = out + (base + e_local) * (size_t)OUT_DIMS + chunk * 4;
    *(float4*)op = a0;
    *(float4*)(op + 64) = a1;
  }
}

extern "C" void kernel_launch(void* const* d_in, const int* in_sizes, int n_in,
                              void* d_out, int out_size, void* d_ws, size_t ws_size,
                              hipStream_t stream) {
  const float* x = (const float*)d_in[0];    // (64, 8192) fp32
  const float* emb = (const float*)d_in[1];  // (64, 128) fp32
  float* out = (float*)d_out;                // (64, 8192, 128) fp32

  const int n = in_sizes[0];                 // 524288 elements
  const int blocks = n / ELEMS_PER_BLOCK;    // 2048
  ce_kernel<<<blocks, BLOCK_THREADS, 0, stream>>>(x, emb, out);
}

// Round 2
// 259.752 us; speedup vs baseline: 1.1579x; 1.0348x over previous
//
#include <hip/hip_runtime.h>
#include <math.h>

#define NUM_POINTS 64
#define OUT_DIMS 128
#define BLOCK_THREADS 512
#define ELEMS_PER_BLOCK 512
#define PAD_LO 4
#define PAD_HI 4
#define LDS_ROWS (NUM_POINTS + PAD_LO + PAD_HI)  // 72 rows

// Weights: w_j = cos^2(pi*d_j/8), d_j = t - j, t = xs - p0 in [3,4).
// cos^2(pi*d/8) = 0.5 + 0.5*cos(pi*d/4); taps spaced pi/4 apart -> all 8
// weights from ONE sin + ONE cos. Interior elements: the 8 cos terms cancel
// exactly (full period), wsum == 4, so weights are built at final scale.
//
// Occupancy: 512 threads x 4 blocks/CU = 2048 threads/CU (max) = 8 waves/SIMD.
// LDS 38 KB x 4 = 152 KB <= 160 KB. launch_bounds(512,8) caps VGPR at 64.
__global__ __launch_bounds__(BLOCK_THREADS, 8) void ce_kernel(
    const float* __restrict__ x,
    const float* __restrict__ emb,
    float* __restrict__ out) {
  __shared__ float s_emb[LDS_ROWS * OUT_DIMS];  // 36864 B, rows -4..67
  __shared__ float s_x[ELEMS_PER_BLOCK];        // 2 KB

  const int tid = threadIdx.x;
  {
    // stage embeddings into rows 4..67 (16B vectorized, coalesced)
    float4* s4 = (float4*)(s_emb + PAD_LO * OUT_DIMS);
    const float4* e4 = (const float4*)emb;
#pragma unroll
    for (int i = 0; i < (NUM_POINTS * OUT_DIMS / 4) / BLOCK_THREADS; ++i)
      s4[tid + i * BLOCK_THREADS] = e4[tid + i * BLOCK_THREADS];
    // zero pad rows (-4..-1, 64..67): OOB taps then contribute 0 with no
    // address clamping in the hot loop.
    if (tid < (PAD_LO * OUT_DIMS / 4)) {
      ((float4*)s_emb)[tid] = make_float4(0.f, 0.f, 0.f, 0.f);
      ((float4*)(s_emb + (PAD_LO + NUM_POINTS) * OUT_DIMS))[tid] =
          make_float4(0.f, 0.f, 0.f, 0.f);
    }
    s_x[tid] = x[blockIdx.x * ELEMS_PER_BLOCK + tid];
  }
  __syncthreads();

  const int chunk = tid & 15;  // 16 dim-chunks: dims [4c,4c+4) and [64+4c,..)
  const int sub = tid >> 4;    // 32 elements per iteration per block
  const size_t base = (size_t)blockIdx.x * ELEMS_PER_BLOCK;
  const float RS2 = 0.70710678118654752f;  // sqrt(2)/2

#pragma unroll 1
  for (int it = 0; it < ELEMS_PER_BLOCK / 32; ++it) {
    const int e_local = it * 32 + sub;
    const float xv = s_x[e_local];         // LDS broadcast per quarter-wave
    const float xs = (xv + 1.0f) * 32.0f;  // [-1,1] -> [0,64]
    const int p0 = (int)xs - 3;            // xs >= 0: trunc == floor
    const float t = xs - (float)p0;        // in [3,4)
    // pi*t/4 rad == t/8 revolutions (v_sin/v_cos take revolutions; t/8 in
    // [0.375,0.5] needs no range reduction)
    const float rev = t * 0.125f;
    const float c4 = 0.125f * __builtin_amdgcn_cosf(rev);
    const float s4 = 0.125f * __builtin_amdgcn_sinf(rev);
    const float u4 = RS2 * (c4 + s4);
    const float v4 = RS2 * (c4 - s4);

    float w[8];
    w[0] = 0.125f + c4;  w[1] = 0.125f + u4;
    w[2] = 0.125f + s4;  w[3] = 0.125f - v4;
    w[4] = 0.125f - c4;  w[5] = 0.125f - u4;
    w[6] = 0.125f - s4;  w[7] = 0.125f + v4;

    // Edge elements (~11%): renormalize over in-grid taps only.
    if (__builtin_expect((unsigned)p0 > 56u, 0)) {
      float ssum = 0.f;
#pragma unroll
      for (int j = 0; j < 8; ++j) {
        w[j] = ((unsigned)(p0 + j) < 64u) ? w[j] : 0.f;
        ssum += w[j];
      }
      const float inv = __builtin_amdgcn_rcpf(ssum);  // ssum >= ~0.24
#pragma unroll
      for (int j = 0; j < 8; ++j) w[j] *= inv;
    }

    // 8 taps x 2 float4 per thread; one base reg + immediate ds offsets.
    const float* rowbase = s_emb + (p0 + PAD_LO) * OUT_DIMS + chunk * 4;
    float4 a0 = make_float4(0.f, 0.f, 0.f, 0.f);
    float4 a1 = make_float4(0.f, 0.f, 0.f, 0.f);
#pragma unroll
    for (int j = 0; j < 8; ++j) {
      const float4 e0 = *(const float4*)(rowbase + j * OUT_DIMS);
      const float4 e1 = *(const float4*)(rowbase + j * OUT_DIMS + 64);
      a0.x = fmaf(w[j], e0.x, a0.x);
      a0.y = fmaf(w[j], e0.y, a0.y);
      a0.z = fmaf(w[j], e0.z, a0.z);
      a0.w = fmaf(w[j], e0.w, a0.w);
      a1.x = fmaf(w[j], e1.x, a1.x);
      a1.y = fmaf(w[j], e1.y, a1.y);
      a1.z = fmaf(w[j], e1.z, a1.z);
      a1.w = fmaf(w[j], e1.w, a1.w);
    }
    // quarter-wave (16 lanes) covers 256B contiguous per store instruction
    float* op = out + (base + e_local) * (size_t)OUT_DIMS + chunk * 4;
    *(float4*)op = a0;
    *(float4*)(op + 64) = a1;
  }
}

extern "C" void kernel_launch(void* const* d_in, const int* in_sizes, int n_in,
                              void* d_out, int out_size, void* d_ws, size_t ws_size,
                              hipStream_t stream) {
  const float* x = (const float*)d_in[0];    // (64, 8192) fp32
  const float* emb = (const float*)d_in[1];  // (64, 128) fp32
  float* out = (float*)d_out;                // (64, 8192, 128) fp32

  const int n = in_sizes[0];                 // 524288 elements
  const int blocks = n / ELEMS_PER_BLOCK;    // 1024 = exactly 4 per CU
  ce_kernel<<<blocks, BLOCK_THREADS, 0, stream>>>(x, emb, out);
}